// Round 7
// baseline (1047.467 us; speedup 1.0000x reference)
//
#include <hip/hip_runtime.h>
#include <hip/hip_bf16.h>

#define A_   8
#define H_   64
#define T_   512
#define B_   32
#define NTOK (B_ * T_)   // 16384 tokens
#define NSEQ (B_ * A_)   // 256 GRU sequences

// ---------------- helpers ----------------

__device__ __forceinline__ float gelu_f(float x) {
    return 0.5f * x * (1.0f + erff(x * 0.70710678118654752440f));
}
__device__ __forceinline__ float fsig(float x)  { return 1.0f / (1.0f + __expf(-x)); }
__device__ __forceinline__ float ftanh(float x) { return 1.0f - 2.0f / (1.0f + __expf(2.0f * x)); }

__device__ __forceinline__ float red16(float v) {
    v += __shfl_xor(v, 1);
    v += __shfl_xor(v, 2);
    v += __shfl_xor(v, 4);
    v += __shfl_xor(v, 8);
    return v;
}
__device__ __forceinline__ float red64(float v) {
    v += __shfl_xor(v, 1);  v += __shfl_xor(v, 2);  v += __shfl_xor(v, 4);
    v += __shfl_xor(v, 8);  v += __shfl_xor(v, 16); v += __shfl_xor(v, 32);
    return v;
}

// LDS-only barrier: s_barrier with lgkmcnt(0) drain but NO vmcnt drain —
// keeps global prefetch loads in flight across the barrier (unlike
// __syncthreads, which emits s_waitcnt vmcnt(0) lgkmcnt(0)).
// Memory-clobber asm on both sides pins LDS ops around the barrier.
__device__ __forceinline__ void barrier_lds() {
    asm volatile("s_waitcnt lgkmcnt(0)" ::: "memory");
    __builtin_amdgcn_s_barrier();
    asm volatile("" ::: "memory");
}

// dual-token matvec: weights loaded ONCE feed both tokens' x-vectors.
template<int KK, int LD>
__device__ __forceinline__ void mv4x2(const float* xa, const float* xb,
                                      const float* Wc, float accA[4], float accB[4]) {
#pragma unroll 4
    for (int k = 0; k < KK; k += 4) {
        float4 w0 = *reinterpret_cast<const float4*>(Wc + (k + 0) * LD);
        float4 w1 = *reinterpret_cast<const float4*>(Wc + (k + 1) * LD);
        float4 w2 = *reinterpret_cast<const float4*>(Wc + (k + 2) * LD);
        float4 w3 = *reinterpret_cast<const float4*>(Wc + (k + 3) * LD);
        float4 va = *reinterpret_cast<const float4*>(xa + k);
        float4 vb = *reinterpret_cast<const float4*>(xb + k);
        accA[0] += va.x * w0.x + va.y * w1.x + va.z * w2.x + va.w * w3.x;
        accA[1] += va.x * w0.y + va.y * w1.y + va.z * w2.y + va.w * w3.y;
        accA[2] += va.x * w0.z + va.y * w1.z + va.z * w2.z + va.w * w3.z;
        accA[3] += va.x * w0.w + va.y * w1.w + va.z * w2.w + va.w * w3.w;
        accB[0] += vb.x * w0.x + vb.y * w1.x + vb.z * w2.x + vb.w * w3.x;
        accB[1] += vb.x * w0.y + vb.y * w1.y + vb.z * w2.y + vb.w * w3.y;
        accB[2] += vb.x * w0.z + vb.y * w1.z + vb.z * w2.z + vb.w * w3.z;
        accB[3] += vb.x * w0.w + vb.y * w1.w + vb.z * w2.w + vb.w * w3.w;
    }
}

__device__ __forceinline__ void ln4(const float v[4], const float* gvec,
                                    const float* bvec, int c0, float out[4]) {
    float s = v[0] + v[1] + v[2] + v[3];
    s = red16(s);
    float m = s * (1.0f / 64.0f);
    float d0 = v[0] - m, d1 = v[1] - m, d2 = v[2] - m, d3 = v[3] - m;
    float ss = d0 * d0 + d1 * d1 + d2 * d2 + d3 * d3;
    ss = red16(ss);
    float inv = rsqrtf(ss * (1.0f / 64.0f) + 1e-5f);
    float4 g = *reinterpret_cast<const float4*>(gvec + c0);
    float4 b = *reinterpret_cast<const float4*>(bvec + c0);
    out[0] = d0 * inv * g.x + b.x;
    out[1] = d1 * inv * g.y + b.y;
    out[2] = d2 * inv * g.z + b.z;
    out[3] = d3 * inv * g.w + b.w;
}

// ---------------- kernel 1: fused per-token pair (r3-proven) ----------------
// 128 threads, block handles tokens n0 and n0+1. Thread = (agent i, lane q),
// owns cols c0..c0+3 of BOTH tokens (weight regs shared across tokens).
// LDS aliasing: P0 = s|a -> K|V ; P1 = se -> tm ; P2 = sae -> nf ;
//               P3 = qe ; P4 = x -> xf.

__global__ __launch_bounds__(128) void token_kernel(
    const float* __restrict__ states, const float* __restrict__ actions,
    const float* __restrict__ sa_W, const float* __restrict__ sa_b,
    const float* __restrict__ sa_g, const float* __restrict__ sa_beta,
    const float* __restrict__ se_W, const float* __restrict__ se_b,
    const float* __restrict__ se_g, const float* __restrict__ se_beta,
    const float* __restrict__ key_W, const float* __restrict__ query_W,
    const float* __restrict__ val_W,
    const float* __restrict__ av_g, const float* __restrict__ av_beta,
    const float* __restrict__ lin1_W, const float* __restrict__ lin1_b,
    const float* __restrict__ lin_g, const float* __restrict__ lin_beta,
    const float* __restrict__ lin2_W, const float* __restrict__ lin2_b,
    const float* __restrict__ avl_g, const float* __restrict__ avl_beta,
    const float* __restrict__ q_W, const float* __restrict__ q_b,
    const float* __restrict__ q_g, const float* __restrict__ q_beta,
    const float* __restrict__ c_W, const float* __restrict__ c_b,
    const float* __restrict__ gru_Wih, const float* __restrict__ gru_bih,
    float* __restrict__ weight_out, float* __restrict__ gi_ws)
{
    const int n0 = blockIdx.x * 2;       // first token of the pair
    const int b = n0 >> 9;               // both tokens share b (T=512, n0 even)
    const int t0 = n0 & 511;
    const int tid = threadIdx.x;
    const int i = tid >> 4;              // agent row 0..7
    const int q = tid & 15;
    const int c0 = 4 * q;

    __shared__ __align__(16) float P0[2][8][152]; // s[0..127],a[136..151] -> K[0..63],V[68..131]
    __shared__ __align__(16) float P1[2][8][68];  // se -> tm
    __shared__ __align__(16) float P2[2][8][68];  // sae -> nf
    __shared__ __align__(16) float P3[2][8][68];  // qe
    __shared__ __align__(16) float P4[2][8][68];  // x -> xf

    // ---- load s (2x8x128) and a (2x8x16) ----
    {
        const float* sbase = states + (size_t)n0 * 1024;
        for (int idx = tid; idx < 512; idx += 128) {
            int tok = idx >> 8, rem = idx & 255;
            int row = rem >> 5, c4 = rem & 31;
            *reinterpret_cast<float4*>(&P0[tok][row][c4 * 4]) =
                *reinterpret_cast<const float4*>(sbase + (size_t)tok * 1024 + row * 128 + c4 * 4);
        }
        const float* abase = actions + (size_t)n0 * 128;
        for (int idx = tid; idx < 256; idx += 128) {
            int tok = idx >> 7, rem = idx & 127;
            int row = rem >> 4, col = rem & 15;
            P0[tok][row][136 + col] = abase[tok * 128 + rem];
        }
    }
    __syncthreads();

    // ---- phase 1: se, sae, qe ----
    {
        float4 bb = *reinterpret_cast<const float4*>(se_b + c0);
        float aA[4] = {bb.x, bb.y, bb.z, bb.w}, aB[4] = {bb.x, bb.y, bb.z, bb.w};
        mv4x2<128, 64>(&P0[0][i][0], &P0[1][i][0], se_W + c0, aA, aB);
        float gA[4] = {gelu_f(aA[0]), gelu_f(aA[1]), gelu_f(aA[2]), gelu_f(aA[3])};
        float gB[4] = {gelu_f(aB[0]), gelu_f(aB[1]), gelu_f(aB[2]), gelu_f(aB[3])};
        float oA[4], oB[4];
        ln4(gA, se_g, se_beta, c0, oA);
        ln4(gB, se_g, se_beta, c0, oB);
        *reinterpret_cast<float4*>(&P1[0][i][c0]) = make_float4(oA[0], oA[1], oA[2], oA[3]);
        *reinterpret_cast<float4*>(&P1[1][i][c0]) = make_float4(oB[0], oB[1], oB[2], oB[3]);
    }
    {
        float4 bb = *reinterpret_cast<const float4*>(sa_b + c0);
        float aA[4] = {bb.x, bb.y, bb.z, bb.w}, aB[4] = {bb.x, bb.y, bb.z, bb.w};
        mv4x2<128, 64>(&P0[0][i][0], &P0[1][i][0], sa_W + c0, aA, aB);
        mv4x2<16, 64>(&P0[0][i][136], &P0[1][i][136], sa_W + 128 * 64 + c0, aA, aB);
        float gA[4] = {gelu_f(aA[0]), gelu_f(aA[1]), gelu_f(aA[2]), gelu_f(aA[3])};
        float gB[4] = {gelu_f(aB[0]), gelu_f(aB[1]), gelu_f(aB[2]), gelu_f(aB[3])};
        float oA[4], oB[4];
        ln4(gA, sa_g, sa_beta, c0, oA);
        ln4(gB, sa_g, sa_beta, c0, oB);
        *reinterpret_cast<float4*>(&P2[0][i][c0]) = make_float4(oA[0], oA[1], oA[2], oA[3]);
        *reinterpret_cast<float4*>(&P2[1][i][c0]) = make_float4(oB[0], oB[1], oB[2], oB[3]);
    }
    {
        float4 bb = *reinterpret_cast<const float4*>(q_b + c0);
        float aA[4] = {bb.x, bb.y, bb.z, bb.w}, aB[4] = {bb.x, bb.y, bb.z, bb.w};
        mv4x2<128, 64>(&P0[0][i][0], &P0[1][i][0], q_W + c0, aA, aB);
        float gA[4] = {gelu_f(aA[0]), gelu_f(aA[1]), gelu_f(aA[2]), gelu_f(aA[3])};
        float gB[4] = {gelu_f(aB[0]), gelu_f(aB[1]), gelu_f(aB[2]), gelu_f(aB[3])};
        float oA[4], oB[4];
        ln4(gA, q_g, q_beta, c0, oA);
        ln4(gB, q_g, q_beta, c0, oB);
        *reinterpret_cast<float4*>(&P3[0][i][c0]) = make_float4(oA[0], oA[1], oA[2], oA[3]);
        *reinterpret_cast<float4*>(&P3[1][i][c0]) = make_float4(oB[0], oB[1], oB[2], oB[3]);
    }
    __syncthreads();   // phase1 reads of P0(s,a) done -> P0 reusable for K,V

    // ---- phase 2: Q (regs), K, V ----
    float QA[4] = {0.f, 0.f, 0.f, 0.f}, QB[4] = {0.f, 0.f, 0.f, 0.f};
    mv4x2<64, 64>(&P1[0][i][0], &P1[1][i][0], query_W + c0, QA, QB);
    {
        float kA[4] = {0.f, 0.f, 0.f, 0.f}, kB[4] = {0.f, 0.f, 0.f, 0.f};
        mv4x2<64, 64>(&P1[0][i][0], &P1[1][i][0], key_W + c0, kA, kB);
        float vA[4] = {0.f, 0.f, 0.f, 0.f}, vB[4] = {0.f, 0.f, 0.f, 0.f};
        mv4x2<64, 64>(&P2[0][i][0], &P2[1][i][0], val_W + c0, vA, vB);
        *reinterpret_cast<float4*>(&P0[0][i][c0])      = make_float4(kA[0], kA[1], kA[2], kA[3]);
        *reinterpret_cast<float4*>(&P0[1][i][c0])      = make_float4(kB[0], kB[1], kB[2], kB[3]);
        *reinterpret_cast<float4*>(&P0[0][i][68 + c0]) = make_float4(vA[0], vA[1], vA[2], vA[3]);
        *reinterpret_cast<float4*>(&P0[1][i][68 + c0]) = make_float4(vB[0], vB[1], vB[2], vB[3]);
    }
    __syncthreads();

    // ---- phase 3: scores, softmax, x = w.V, ln ----
    float scA[8], scB[8];
#pragma unroll
    for (int k = 0; k < 8; k++) {
        float4 ka = *reinterpret_cast<const float4*>(&P0[0][k][c0]);
        float pA = QA[0] * ka.x + QA[1] * ka.y + QA[2] * ka.z + QA[3] * ka.w;
        scA[k] = red16(pA) * 0.125f;
        float4 kb = *reinterpret_cast<const float4*>(&P0[1][k][c0]);
        float pB = QB[0] * kb.x + QB[1] * kb.y + QB[2] * kb.z + QB[3] * kb.w;
        scB[k] = red16(pB) * 0.125f;
    }
    float wsmA[8], wsmB[8];
    {
        float mxA = -1e30f, mxB = -1e30f;
#pragma unroll
        for (int k = 0; k < 8; k++) if (k != i) { mxA = fmaxf(mxA, scA[k]); mxB = fmaxf(mxB, scB[k]); }
        float suA = 0.f, suB = 0.f;
#pragma unroll
        for (int k = 0; k < 8; k++) {
            float eA = (k == i) ? 0.0f : __expf(scA[k] - mxA);
            float eB = (k == i) ? 0.0f : __expf(scB[k] - mxB);
            wsmA[k] = eA; suA += eA;
            wsmB[k] = eB; suB += eB;
        }
        float rA = 1.0f / suA, rB = 1.0f / suB;
#pragma unroll
        for (int k = 0; k < 8; k++) { wsmA[k] *= rA; wsmB[k] *= rB; }
    }
    if (q < 7) {
        int kk = q + (q >= i ? 1 : 0);
        float wA = 0.f, wB = 0.f;
#pragma unroll
        for (int k = 0; k < 8; k++) if (kk == k) { wA = wsmA[k]; wB = wsmB[k]; }
        weight_out[((size_t)n0 * A_ + i) * 7 + q] = wA;
        weight_out[((size_t)(n0 + 1) * A_ + i) * 7 + q] = wB;
    }
    float xaA[4], xaB[4];
    {
        float xA[4] = {0.f, 0.f, 0.f, 0.f}, xB[4] = {0.f, 0.f, 0.f, 0.f};
#pragma unroll
        for (int k = 0; k < 8; k++) {
            float4 va = *reinterpret_cast<const float4*>(&P0[0][k][68 + c0]);
            float4 vb = *reinterpret_cast<const float4*>(&P0[1][k][68 + c0]);
            float wA = wsmA[k], wB = wsmB[k];
            xA[0] += wA * va.x; xA[1] += wA * va.y; xA[2] += wA * va.z; xA[3] += wA * va.w;
            xB[0] += wB * vb.x; xB[1] += wB * vb.y; xB[2] += wB * vb.z; xB[3] += wB * vb.w;
        }
        ln4(xA, av_g, av_beta, c0, xaA);
        ln4(xB, av_g, av_beta, c0, xaB);
        *reinterpret_cast<float4*>(&P4[0][i][c0]) = make_float4(xaA[0], xaA[1], xaA[2], xaA[3]);
        *reinterpret_cast<float4*>(&P4[1][i][c0]) = make_float4(xaB[0], xaB[1], xaB[2], xaB[3]);
    }
    __syncthreads();

    // ---- phase 4a: lin1 -> tm (P1) ----
    {
        float4 bb = *reinterpret_cast<const float4*>(lin1_b + c0);
        float aA[4] = {bb.x, bb.y, bb.z, bb.w}, aB[4] = {bb.x, bb.y, bb.z, bb.w};
        mv4x2<64, 64>(&P4[0][i][0], &P4[1][i][0], lin1_W + c0, aA, aB);
        float gA[4] = {gelu_f(aA[0]), gelu_f(aA[1]), gelu_f(aA[2]), gelu_f(aA[3])};
        float gB[4] = {gelu_f(aB[0]), gelu_f(aB[1]), gelu_f(aB[2]), gelu_f(aB[3])};
        float oA[4], oB[4];
        ln4(gA, lin_g, lin_beta, c0, oA);
        ln4(gB, lin_g, lin_beta, c0, oB);
        *reinterpret_cast<float4*>(&P1[0][i][c0]) = make_float4(oA[0], oA[1], oA[2], oA[3]);
        *reinterpret_cast<float4*>(&P1[1][i][c0]) = make_float4(oB[0], oB[1], oB[2], oB[3]);
    }
    __syncthreads();

    // ---- phase 4b: lin2, xf = ln(x + x_) -> P4 ----
    {
        float4 bb = *reinterpret_cast<const float4*>(lin2_b + c0);
        float aA[4] = {bb.x, bb.y, bb.z, bb.w}, aB[4] = {bb.x, bb.y, bb.z, bb.w};
        mv4x2<64, 64>(&P1[0][i][0], &P1[1][i][0], lin2_W + c0, aA, aB);
        float sA[4] = {xaA[0] + aA[0], xaA[1] + aA[1], xaA[2] + aA[2], xaA[3] + aA[3]};
        float sB[4] = {xaB[0] + aB[0], xaB[1] + aB[1], xaB[2] + aB[2], xaB[3] + aB[3]};
        float oA[4], oB[4];
        ln4(sA, avl_g, avl_beta, c0, oA);
        ln4(sB, avl_g, avl_beta, c0, oB);
        *reinterpret_cast<float4*>(&P4[0][i][c0]) = make_float4(oA[0], oA[1], oA[2], oA[3]);
        *reinterpret_cast<float4*>(&P4[1][i][c0]) = make_float4(oB[0], oB[1], oB[2], oB[3]);
    }
    __syncthreads();

    // ---- phase 4c: nf = gelu([qe, xf] @ c_W + c_b) -> P2 ----
    {
        float4 bb = *reinterpret_cast<const float4*>(c_b + c0);
        float aA[4] = {bb.x, bb.y, bb.z, bb.w}, aB[4] = {bb.x, bb.y, bb.z, bb.w};
        mv4x2<64, 64>(&P3[0][i][0], &P3[1][i][0], c_W + c0, aA, aB);
        mv4x2<64, 64>(&P4[0][i][0], &P4[1][i][0], c_W + 64 * 64 + c0, aA, aB);
        float gA[4] = {gelu_f(aA[0]), gelu_f(aA[1]), gelu_f(aA[2]), gelu_f(aA[3])};
        float gB[4] = {gelu_f(aB[0]), gelu_f(aB[1]), gelu_f(aB[2]), gelu_f(aB[3])};
        *reinterpret_cast<float4*>(&P2[0][i][c0]) = make_float4(gA[0], gA[1], gA[2], gA[3]);
        *reinterpret_cast<float4*>(&P2[1][i][c0]) = make_float4(gB[0], gB[1], gB[2], gB[3]);
    }
    __syncthreads();

    // ---- phase 4d: gi = nf @ gru_Wih + gru_bih -> gi_ws[seq][t][192] ----
    {
        const int seq = b * A_ + i;
        float* goutA = gi_ws + ((size_t)seq * T_ + t0) * 192;
        float* goutB = goutA + 192;
#pragma unroll
        for (int m3 = 0; m3 < 3; m3++) {
            float4 bb = *reinterpret_cast<const float4*>(gru_bih + m3 * 64 + c0);
            float aA[4] = {bb.x, bb.y, bb.z, bb.w}, aB[4] = {bb.x, bb.y, bb.z, bb.w};
            mv4x2<64, 192>(&P2[0][i][0], &P2[1][i][0], gru_Wih + m3 * 64 + c0, aA, aB);
            *reinterpret_cast<float4*>(goutA + m3 * 64 + c0) = make_float4(aA[0], aA[1], aA[2], aA[3]);
            *reinterpret_cast<float4*>(goutB + m3 * 64 + c0) = make_float4(aB[0], aB[1], aB[2], aB[3]);
        }
    }
}

// ---------------- kernel 2: GRU scan ----------------
// one block per sequence; 192 threads compute gh[jj]; wave 0 (jj<64) does the
// gates with gi prefetched 2 steps ahead straight from global, and writes h_t
// back into the first 64 floats of the (already consumed) gi slot t.
// barrier_lds() (lgkmcnt-only) keeps the prefetch loads in flight across
// barriers — __syncthreads would drain vmcnt(0) every step.

#define GRU_STEP(T_IDX, GR, GZ, GN)                                            \
    {                                                                          \
        float a0 = 0.f, a1 = 0.f, a2 = 0.f, a3 = 0.f;                          \
        _Pragma("unroll")                                                      \
        for (int k = 0; k < 64; k += 4) {                                      \
            float4 hv = *reinterpret_cast<const float4*>(&h_lds[k]);           \
            a0 += hv.x * wcol[k + 0];                                          \
            a1 += hv.y * wcol[k + 1];                                          \
            a2 += hv.z * wcol[k + 2];                                          \
            a3 += hv.w * wcol[k + 3];                                          \
        }                                                                      \
        float gh = (a0 + a1) + (a2 + a3) + bhh_r;                              \
        gh_lds[jj] = gh;                                                       \
        barrier_lds();                                                         \
        if (jj < 64) {                                                         \
            float rg = fsig(GR + gh);                                          \
            float zg = fsig(GZ + gh_lds[64 + jj]);                             \
            float ng = ftanh(GN + rg * gh_lds[128 + jj]);                      \
            float hold = h_lds[jj];                                            \
            float hnew = ng + zg * (hold - ng);                                \
            h_lds[jj] = hnew;                                                  \
            gbase[(size_t)(T_IDX) * 192 + jj] = hnew;                          \
            int tp = ((T_IDX) + 2 < T_) ? (T_IDX) + 2 : 510;                   \
            GR = gbase[(size_t)tp * 192 + jj];                                 \
            GZ = gbase[(size_t)tp * 192 + 64 + jj];                            \
            GN = gbase[(size_t)tp * 192 + 128 + jj];                           \
        }                                                                      \
        barrier_lds();                                                         \
    }

__global__ __launch_bounds__(192) void gru_kernel(
    const float* __restrict__ h0, const float* __restrict__ gru_Whh,
    const float* __restrict__ gru_bhh, float* __restrict__ gi_ws,
    float* __restrict__ hT_out)
{
    const int seq = blockIdx.x;     // 0..255
    const int jj = threadIdx.x;     // 0..191

    __shared__ __align__(16) float h_lds[64];
    __shared__ __align__(16) float gh_lds[192];

    float wcol[64];
#pragma unroll
    for (int k = 0; k < 64; k++) wcol[k] = gru_Whh[k * 192 + jj];
    const float bhh_r = gru_bhh[jj];

    float* gbase = gi_ws + (size_t)seq * T_ * 192;

    float grA = 0.f, gzA = 0.f, gnA = 0.f, grB = 0.f, gzB = 0.f, gnB = 0.f;
    if (jj < 64) {
        h_lds[jj] = h0[(size_t)seq * 64 + jj];
        grA = gbase[jj];        gzA = gbase[64 + jj];        gnA = gbase[128 + jj];
        grB = gbase[192 + jj];  gzB = gbase[192 + 64 + jj];  gnB = gbase[192 + 128 + jj];
    }
    __syncthreads();

    for (int t = 0; t < T_; t += 2) {
        GRU_STEP(t,     grA, gzA, gnA)
        GRU_STEP(t + 1, grB, gzB, gnB)
    }
    if (jj < 64) hT_out[(size_t)seq * 64 + jj] = h_lds[jj];
}

// ---------------- kernel 3: Value = ln(h, f) @ f_W + f_b ----------------
// reads h_t from gi_ws slots (first 64 floats of each 192-float slot)

__global__ __launch_bounds__(256) void value_kernel(
    const float* __restrict__ gi_ws, const float* __restrict__ f_g,
    const float* __restrict__ f_beta, const float* __restrict__ f_W,
    const float* __restrict__ f_b, float* __restrict__ value_out)
{
    const int r = blockIdx.x * 4 + (threadIdx.x >> 6);  // row = n*8 + i
    const int j = threadIdx.x & 63;
    const int n = r >> 3, i = r & 7;
    const int b = n >> 9, t = n & 511;
    const int seq = b * A_ + i;

    float h = gi_ws[((size_t)seq * T_ + t) * 192 + j];
    float m = red64(h) * (1.0f / 64.0f);
    float d = h - m;
    float v = red64(d * d) * (1.0f / 64.0f);
    float nrm = d * rsqrtf(v + 1e-5f) * f_g[j] + f_beta[j];
    float p = red64(nrm * f_W[j]);
    if (j == 0) value_out[r] = p + f_b[0];
}

// ---------------- launch ----------------

extern "C" void kernel_launch(void* const* d_in, const int* in_sizes, int n_in,
                              void* d_out, int out_size, void* d_ws, size_t ws_size,
                              hipStream_t stream) {
    (void)in_sizes; (void)n_in; (void)out_size; (void)ws_size;

    const float* states   = (const float*)d_in[0];
    const float* actions  = (const float*)d_in[1];
    const float* h0       = (const float*)d_in[2];
    const float* sa_W     = (const float*)d_in[3];
    const float* sa_b     = (const float*)d_in[4];
    const float* sa_g     = (const float*)d_in[5];
    const float* sa_beta  = (const float*)d_in[6];
    const float* se_W     = (const float*)d_in[7];
    const float* se_b     = (const float*)d_in[8];
    const float* se_g     = (const float*)d_in[9];
    const float* se_beta  = (const float*)d_in[10];
    const float* key_W    = (const float*)d_in[11];
    const float* query_W  = (const float*)d_in[12];
    const float* val_W    = (const float*)d_in[13];
    const float* av_g     = (const float*)d_in[14];
    const float* av_beta  = (const float*)d_in[15];
    const float* lin1_W   = (const float*)d_in[16];
    const float* lin1_b   = (const float*)d_in[17];
    const float* lin_g    = (const float*)d_in[18];
    const float* lin_beta = (const float*)d_in[19];
    const float* lin2_W   = (const float*)d_in[20];
    const float* lin2_b   = (const float*)d_in[21];
    const float* avl_g    = (const float*)d_in[22];
    const float* avl_beta = (const float*)d_in[23];
    const float* q_W      = (const float*)d_in[24];
    const float* q_b      = (const float*)d_in[25];
    const float* q_g      = (const float*)d_in[26];
    const float* q_beta   = (const float*)d_in[27];
    const float* c_W      = (const float*)d_in[28];
    const float* c_b      = (const float*)d_in[29];
    const float* gru_Wih  = (const float*)d_in[30];
    const float* gru_Whh  = (const float*)d_in[31];
    const float* gru_bih  = (const float*)d_in[32];
    const float* gru_bhh  = (const float*)d_in[33];
    const float* f_g      = (const float*)d_in[34];
    const float* f_beta   = (const float*)d_in[35];
    const float* f_W      = (const float*)d_in[36];
    const float* f_b      = (const float*)d_in[37];

    float* out = (float*)d_out;
    float* value_out  = out;                          // 131072
    float* weight_out = out + (size_t)NTOK * A_;      // 917504
    float* hT_out     = out + (size_t)NTOK * A_ * 8;  // 16384

    float* gi_ws = (float*)d_ws;                      // [256][512][192] f32 = 96 MiB

    token_kernel<<<NTOK / 2, 128, 0, stream>>>(
        states, actions,
        sa_W, sa_b, sa_g, sa_beta,
        se_W, se_b, se_g, se_beta,
        key_W, query_W, val_W,
        av_g, av_beta,
        lin1_W, lin1_b, lin_g, lin_beta,
        lin2_W, lin2_b,
        avl_g, avl_beta,
        q_W, q_b, q_g, q_beta,
        c_W, c_b,
        gru_Wih, gru_bih,
        weight_out, gi_ws);

    gru_kernel<<<NSEQ, 192, 0, stream>>>(h0, gru_Whh, gru_bhh, gi_ws, hT_out);

    value_kernel<<<(NTOK * A_) / 4, 256, 0, stream>>>(
        gi_ws, f_g, f_beta, f_W, f_b, value_out);
}

// Round 9
// 914.826 us; speedup vs baseline: 1.1450x; 1.1450x over previous
//
#include <hip/hip_runtime.h>
#include <hip/hip_bf16.h>

#define A_   8
#define H_   64
#define T_   512
#define B_   32
#define NTOK (B_ * T_)   // 16384 tokens
#define NSEQ (B_ * A_)   // 256 GRU sequences
#define TPB  4           // tokens per token_kernel block

#define GI_FLOATS (256u * 512u * 192u)   // 96 MiB of f32 in d_ws
// rnn_ws = d_ws + GI_FLOATS : [256][512][64] f32 = 32 MiB (ws >= 128 MiB proven r2)

// ---------------- helpers ----------------

__device__ __forceinline__ float gelu_f(float x) {
    return 0.5f * x * (1.0f + erff(x * 0.70710678118654752440f));
}
__device__ __forceinline__ float fsig(float x)  { return 1.0f / (1.0f + __expf(-x)); }
__device__ __forceinline__ float ftanh(float x) { return 1.0f - 2.0f / (1.0f + __expf(2.0f * x)); }

__device__ __forceinline__ float red16(float v) {
    v += __shfl_xor(v, 1);
    v += __shfl_xor(v, 2);
    v += __shfl_xor(v, 4);
    v += __shfl_xor(v, 8);
    return v;
}
__device__ __forceinline__ float red64(float v) {
    v += __shfl_xor(v, 1);  v += __shfl_xor(v, 2);  v += __shfl_xor(v, 4);
    v += __shfl_xor(v, 8);  v += __shfl_xor(v, 16); v += __shfl_xor(v, 32);
    return v;
}

// LDS-only barrier: lgkmcnt(0) drain + s_barrier, NO vmcnt drain — global
// prefetch loads stay in flight across it.
__device__ __forceinline__ void barrier_lds() {
    asm volatile("s_waitcnt lgkmcnt(0)" ::: "memory");
    __builtin_amdgcn_s_barrier();
    asm volatile("" ::: "memory");
}

// broadcast lane k of x to all lanes via v_readlane (SGPR path, no DS pipe)
#define RL(x, k) __int_as_float(__builtin_amdgcn_readlane(__float_as_int(x), (k)))

// multi-token matvec: 4 weight float4 loads feed TPB tokens' accumulators.
// x0 = &P[0][i][0]; xstride = floats between consecutive tokens' tiles.
template<int KK, int LD>
__device__ __forceinline__ void mvT(const float* x0, int xstride, const float* Wc,
                                    float acc[TPB][4]) {
#pragma unroll 4
    for (int k = 0; k < KK; k += 4) {
        float4 w0 = *reinterpret_cast<const float4*>(Wc + (k + 0) * LD);
        float4 w1 = *reinterpret_cast<const float4*>(Wc + (k + 1) * LD);
        float4 w2 = *reinterpret_cast<const float4*>(Wc + (k + 2) * LD);
        float4 w3 = *reinterpret_cast<const float4*>(Wc + (k + 3) * LD);
#pragma unroll
        for (int tt = 0; tt < TPB; tt++) {
            float4 xv = *reinterpret_cast<const float4*>(x0 + tt * xstride + k);
            acc[tt][0] += xv.x * w0.x + xv.y * w1.x + xv.z * w2.x + xv.w * w3.x;
            acc[tt][1] += xv.x * w0.y + xv.y * w1.y + xv.z * w2.y + xv.w * w3.y;
            acc[tt][2] += xv.x * w0.z + xv.y * w1.z + xv.z * w2.z + xv.w * w3.z;
            acc[tt][3] += xv.x * w0.w + xv.y * w1.w + xv.z * w2.w + xv.w * w3.w;
        }
    }
}

__device__ __forceinline__ void ln4(const float v[4], const float* gvec,
                                    const float* bvec, int c0, float out[4]) {
    float s = v[0] + v[1] + v[2] + v[3];
    s = red16(s);
    float m = s * (1.0f / 64.0f);
    float d0 = v[0] - m, d1 = v[1] - m, d2 = v[2] - m, d3 = v[3] - m;
    float ss = d0 * d0 + d1 * d1 + d2 * d2 + d3 * d3;
    ss = red16(ss);
    float inv = rsqrtf(ss * (1.0f / 64.0f) + 1e-5f);
    float4 g = *reinterpret_cast<const float4*>(gvec + c0);
    float4 b = *reinterpret_cast<const float4*>(bvec + c0);
    out[0] = d0 * inv * g.x + b.x;
    out[1] = d1 * inv * g.y + b.y;
    out[2] = d2 * inv * g.z + b.z;
    out[3] = d3 * inv * g.w + b.w;
}

#define BIAS_INIT(acc, bptr)                                                  \
    {                                                                          \
        float4 bb = *reinterpret_cast<const float4*>((bptr) + c0);             \
        _Pragma("unroll")                                                      \
        for (int tt = 0; tt < TPB; tt++) {                                     \
            acc[tt][0] = bb.x; acc[tt][1] = bb.y;                              \
            acc[tt][2] = bb.z; acc[tt][3] = bb.w;                              \
        }                                                                      \
    }

// ---------------- kernel 1: fused per-token quad (f32, r3-proven math) ----------------
// 128 threads: agent i = tid>>4, lane q = tid&15, cols c0..c0+3 of ALL TPB tokens.

__global__ __launch_bounds__(128) void token_kernel(
    const float* __restrict__ states, const float* __restrict__ actions,
    const float* __restrict__ sa_W, const float* __restrict__ sa_b,
    const float* __restrict__ sa_g, const float* __restrict__ sa_beta,
    const float* __restrict__ se_W, const float* __restrict__ se_b,
    const float* __restrict__ se_g, const float* __restrict__ se_beta,
    const float* __restrict__ key_W, const float* __restrict__ query_W,
    const float* __restrict__ val_W,
    const float* __restrict__ av_g, const float* __restrict__ av_beta,
    const float* __restrict__ lin1_W, const float* __restrict__ lin1_b,
    const float* __restrict__ lin_g, const float* __restrict__ lin_beta,
    const float* __restrict__ lin2_W, const float* __restrict__ lin2_b,
    const float* __restrict__ avl_g, const float* __restrict__ avl_beta,
    const float* __restrict__ q_W, const float* __restrict__ q_b,
    const float* __restrict__ q_g, const float* __restrict__ q_beta,
    const float* __restrict__ c_W, const float* __restrict__ c_b,
    const float* __restrict__ gru_Wih, const float* __restrict__ gru_bih,
    float* __restrict__ weight_out, float* __restrict__ gi_ws)
{
    const int n0 = blockIdx.x * TPB;     // first token of the quad
    const int b = n0 >> 9;               // all TPB tokens share b (t0 % TPB == 0)
    const int t0 = n0 & 511;
    const int tid = threadIdx.x;
    const int i = tid >> 4;              // agent row 0..7
    const int q = tid & 15;
    const int c0 = 4 * q;

    __shared__ __align__(16) float P0[TPB][8][152]; // s|a -> K[0..63], V[68..131]
    __shared__ __align__(16) float P1[TPB][8][68];  // se -> tm
    __shared__ __align__(16) float P2[TPB][8][68];  // sae -> nf
    __shared__ __align__(16) float P3[TPB][8][68];  // qe
    __shared__ __align__(16) float P4[TPB][8][68];  // x -> xf
    const int S0 = 8 * 152, S1 = 8 * 68;

    // ---- load s (TPBx8x128) and a (TPBx8x16) ----
    {
        const float* sbase = states + (size_t)n0 * 1024;
        for (int idx = tid; idx < TPB * 256; idx += 128) {
            int tok = idx >> 8, rem = idx & 255;
            *reinterpret_cast<float4*>(&P0[tok][rem >> 5][(rem & 31) * 4]) =
                *reinterpret_cast<const float4*>(sbase + (size_t)tok * 1024 + rem * 4);
        }
        const float* abase = actions + (size_t)n0 * 128;
        for (int idx = tid; idx < TPB * 128; idx += 128) {
            int tok = idx >> 7, rem = idx & 127;
            P0[tok][rem >> 4][136 + (rem & 15)] = abase[tok * 128 + rem];
        }
    }
    __syncthreads();

    // ---- phase 1: se, sae, qe ----
    {
        float acc[TPB][4];
        BIAS_INIT(acc, se_b)
        mvT<128, 64>(&P0[0][i][0], S0, se_W + c0, acc);
#pragma unroll
        for (int tt = 0; tt < TPB; tt++) {
            float gv[4] = {gelu_f(acc[tt][0]), gelu_f(acc[tt][1]), gelu_f(acc[tt][2]), gelu_f(acc[tt][3])};
            float o[4];
            ln4(gv, se_g, se_beta, c0, o);
            *reinterpret_cast<float4*>(&P1[tt][i][c0]) = make_float4(o[0], o[1], o[2], o[3]);
        }
    }
    {
        float acc[TPB][4];
        BIAS_INIT(acc, sa_b)
        mvT<128, 64>(&P0[0][i][0], S0, sa_W + c0, acc);
        mvT<16, 64>(&P0[0][i][136], S0, sa_W + 128 * 64 + c0, acc);
#pragma unroll
        for (int tt = 0; tt < TPB; tt++) {
            float gv[4] = {gelu_f(acc[tt][0]), gelu_f(acc[tt][1]), gelu_f(acc[tt][2]), gelu_f(acc[tt][3])};
            float o[4];
            ln4(gv, sa_g, sa_beta, c0, o);
            *reinterpret_cast<float4*>(&P2[tt][i][c0]) = make_float4(o[0], o[1], o[2], o[3]);
        }
    }
    {
        float acc[TPB][4];
        BIAS_INIT(acc, q_b)
        mvT<128, 64>(&P0[0][i][0], S0, q_W + c0, acc);
#pragma unroll
        for (int tt = 0; tt < TPB; tt++) {
            float gv[4] = {gelu_f(acc[tt][0]), gelu_f(acc[tt][1]), gelu_f(acc[tt][2]), gelu_f(acc[tt][3])};
            float o[4];
            ln4(gv, q_g, q_beta, c0, o);
            *reinterpret_cast<float4*>(&P3[tt][i][c0]) = make_float4(o[0], o[1], o[2], o[3]);
        }
    }
    __syncthreads();   // phase-1 reads of P0 retired -> P0 reusable for K,V

    // ---- phase 2: Q (regs), K, V ----
    float Qr[TPB][4];
#pragma unroll
    for (int tt = 0; tt < TPB; tt++) { Qr[tt][0] = Qr[tt][1] = Qr[tt][2] = Qr[tt][3] = 0.f; }
    mvT<64, 64>(&P1[0][i][0], S1, query_W + c0, Qr);
    {
        float kA[TPB][4], vA[TPB][4];
#pragma unroll
        for (int tt = 0; tt < TPB; tt++) {
            kA[tt][0] = kA[tt][1] = kA[tt][2] = kA[tt][3] = 0.f;
            vA[tt][0] = vA[tt][1] = vA[tt][2] = vA[tt][3] = 0.f;
        }
        mvT<64, 64>(&P1[0][i][0], S1, key_W + c0, kA);
        mvT<64, 64>(&P2[0][i][0], S1, val_W + c0, vA);
#pragma unroll
        for (int tt = 0; tt < TPB; tt++) {
            *reinterpret_cast<float4*>(&P0[tt][i][c0])      = make_float4(kA[tt][0], kA[tt][1], kA[tt][2], kA[tt][3]);
            *reinterpret_cast<float4*>(&P0[tt][i][68 + c0]) = make_float4(vA[tt][0], vA[tt][1], vA[tt][2], vA[tt][3]);
        }
    }
    __syncthreads();

    // ---- phase 3: scores, masked softmax, weight_out, x = w.V, ln(av) ----
    float xa[TPB][4];
#pragma unroll
    for (int tt = 0; tt < TPB; tt++) {
        float sc[8];
#pragma unroll
        for (int k = 0; k < 8; k++) {
            float4 kv = *reinterpret_cast<const float4*>(&P0[tt][k][c0]);
            float p = Qr[tt][0] * kv.x + Qr[tt][1] * kv.y + Qr[tt][2] * kv.z + Qr[tt][3] * kv.w;
            sc[k] = red16(p) * 0.125f;
        }
        float mx = -1e30f;
#pragma unroll
        for (int k = 0; k < 8; k++) if (k != i) mx = fmaxf(mx, sc[k]);
        float wsm[8];
        float sum = 0.f;
#pragma unroll
        for (int k = 0; k < 8; k++) {
            float e = (k == i) ? 0.0f : __expf(sc[k] - mx);
            wsm[k] = e; sum += e;
        }
        float rinv = 1.0f / sum;
#pragma unroll
        for (int k = 0; k < 8; k++) wsm[k] *= rinv;
        if (q < 7) {
            int kk = q + (q >= i ? 1 : 0);
            float wo = 0.f;
#pragma unroll
            for (int k = 0; k < 8; k++) if (kk == k) wo = wsm[k];
            weight_out[((size_t)(n0 + tt) * A_ + i) * 7 + q] = wo;
        }
        float xr[4] = {0.f, 0.f, 0.f, 0.f};
#pragma unroll
        for (int k = 0; k < 8; k++) {
            float4 vv = *reinterpret_cast<const float4*>(&P0[tt][k][68 + c0]);
            float wk = wsm[k];
            xr[0] += wk * vv.x; xr[1] += wk * vv.y; xr[2] += wk * vv.z; xr[3] += wk * vv.w;
        }
        ln4(xr, av_g, av_beta, c0, xa[tt]);
        *reinterpret_cast<float4*>(&P4[tt][i][c0]) =
            make_float4(xa[tt][0], xa[tt][1], xa[tt][2], xa[tt][3]);
    }
    __syncthreads();

    // ---- phase 4a: tm = ln(gelu(x @ lin1 + b)) -> P1 ----
    {
        float acc[TPB][4];
        BIAS_INIT(acc, lin1_b)
        mvT<64, 64>(&P4[0][i][0], S1, lin1_W + c0, acc);
#pragma unroll
        for (int tt = 0; tt < TPB; tt++) {
            float gv[4] = {gelu_f(acc[tt][0]), gelu_f(acc[tt][1]), gelu_f(acc[tt][2]), gelu_f(acc[tt][3])};
            float o[4];
            ln4(gv, lin_g, lin_beta, c0, o);
            *reinterpret_cast<float4*>(&P1[tt][i][c0]) = make_float4(o[0], o[1], o[2], o[3]);
        }
    }
    __syncthreads();

    // ---- phase 4b: xf = ln(x + tm @ lin2 + b, avl) -> P4 ----
    {
        float acc[TPB][4];
        BIAS_INIT(acc, lin2_b)
        mvT<64, 64>(&P1[0][i][0], S1, lin2_W + c0, acc);
#pragma unroll
        for (int tt = 0; tt < TPB; tt++) {
            float sv[4] = {xa[tt][0] + acc[tt][0], xa[tt][1] + acc[tt][1],
                           xa[tt][2] + acc[tt][2], xa[tt][3] + acc[tt][3]};
            float o[4];
            ln4(sv, avl_g, avl_beta, c0, o);
            *reinterpret_cast<float4*>(&P4[tt][i][c0]) = make_float4(o[0], o[1], o[2], o[3]);
        }
    }
    __syncthreads();

    // ---- phase 4c: nf = gelu([qe, xf] @ c_W + c_b) -> P2 ----
    {
        float acc[TPB][4];
        BIAS_INIT(acc, c_b)
        mvT<64, 64>(&P3[0][i][0], S1, c_W + c0, acc);
        mvT<64, 64>(&P4[0][i][0], S1, c_W + 64 * 64 + c0, acc);
#pragma unroll
        for (int tt = 0; tt < TPB; tt++) {
            float gv[4] = {gelu_f(acc[tt][0]), gelu_f(acc[tt][1]), gelu_f(acc[tt][2]), gelu_f(acc[tt][3])};
            *reinterpret_cast<float4*>(&P2[tt][i][c0]) = make_float4(gv[0], gv[1], gv[2], gv[3]);
        }
    }
    __syncthreads();

    // ---- phase 4d: gi = nf @ gru_Wih + gru_bih -> gi_ws[seq][t][192] ----
    {
        const int seq = b * A_ + i;
#pragma unroll
        for (int m3 = 0; m3 < 3; m3++) {
            float acc[TPB][4];
            {
                float4 bb = *reinterpret_cast<const float4*>(gru_bih + m3 * 64 + c0);
#pragma unroll
                for (int tt = 0; tt < TPB; tt++) {
                    acc[tt][0] = bb.x; acc[tt][1] = bb.y; acc[tt][2] = bb.z; acc[tt][3] = bb.w;
                }
            }
            mvT<64, 192>(&P2[0][i][0], S1, gru_Wih + m3 * 64 + c0, acc);
#pragma unroll
            for (int tt = 0; tt < TPB; tt++) {
                float* gout = gi_ws + ((size_t)seq * T_ + (t0 + tt)) * 192;
                *reinterpret_cast<float4*>(gout + m3 * 64 + c0) =
                    make_float4(acc[tt][0], acc[tt][1], acc[tt][2], acc[tt][3]);
            }
        }
    }
}

// ---------------- kernel 2: GRU scan (readlane matvec, register h) ----------------
// 192 threads = 3 waves; thread jj owns gate column jj; j = jj&63.
// ALL waves redundantly hold h[lane] in a register and compute the full gate
// set — only gh crosses waves (1 ds_write + 1 lgkm-barrier + 3 ds_read per
// step, double-buffered). h_t goes to rnn_ws (gi slots never overwritten, so
// the 2-ahead all-wave gi prefetch has no cross-thread hazard).

#define GRU_STEP(T_IDX, PBUF, GR, GZ, GN)                                      \
    {                                                                          \
        float a0 = 0.f, a1 = 0.f, a2 = 0.f, a3 = 0.f;                          \
        _Pragma("unroll")                                                      \
        for (int k = 0; k < 64; k += 4) {                                      \
            a0 = fmaf(RL(h, k + 0), wcol[k + 0], a0);                          \
            a1 = fmaf(RL(h, k + 1), wcol[k + 1], a1);                          \
            a2 = fmaf(RL(h, k + 2), wcol[k + 2], a2);                          \
            a3 = fmaf(RL(h, k + 3), wcol[k + 3], a3);                          \
        }                                                                      \
        gh_lds[PBUF][jj] = (a0 + a1) + (a2 + a3) + bh;                         \
        barrier_lds();                                                         \
        float rg = fsig(GR + gh_lds[PBUF][j]);                                 \
        float zg = fsig(GZ + gh_lds[PBUF][64 + j]);                            \
        float ng = ftanh(GN + rg * gh_lds[PBUF][128 + j]);                     \
        h = ng + zg * (h - ng);                                                \
        if (jj < 64) rnn_seq[(size_t)(T_IDX) * 64 + jj] = h;                   \
        {                                                                      \
            int tp = ((T_IDX) + 2) & 511;                                      \
            GR = gbase[(size_t)tp * 192 + j];                                  \
            GZ = gbase[(size_t)tp * 192 + 64 + j];                             \
            GN = gbase[(size_t)tp * 192 + 128 + j];                            \
        }                                                                      \
    }

__global__ __launch_bounds__(192) void gru_kernel(
    const float* __restrict__ h0, const float* __restrict__ gru_Whh,
    const float* __restrict__ gru_bhh, const float* __restrict__ gi_ws,
    float* __restrict__ rnn_ws, float* __restrict__ hT_out)
{
    const int seq = blockIdx.x;     // 0..255
    const int jj = threadIdx.x;     // 0..191 (gate column)
    const int j = jj & 63;          // h index this thread finalizes

    __shared__ float gh_lds[2][192];

    float wcol[64];
#pragma unroll
    for (int k = 0; k < 64; k++) wcol[k] = gru_Whh[k * 192 + jj];
    const float bh = gru_bhh[jj];

    const float* gbase = gi_ws + (size_t)seq * T_ * 192;
    float* rnn_seq = rnn_ws + (size_t)seq * T_ * 64;

    float h = h0[(size_t)seq * 64 + j];          // every thread holds h[j]
    float grA = gbase[j],       gzA = gbase[64 + j],       gnA = gbase[128 + j];
    float grB = gbase[192 + j], gzB = gbase[192 + 64 + j], gnB = gbase[192 + 128 + j];

    for (int t = 0; t < T_; t += 2) {
        GRU_STEP(t,     0, grA, gzA, gnA)
        GRU_STEP(t + 1, 1, grB, gzB, gnB)
    }
    if (jj < 64) hT_out[(size_t)seq * 64 + jj] = h;
}

// ---------------- kernel 3: Value = ln(h, f) @ f_W + f_b ----------------

__global__ __launch_bounds__(256) void value_kernel(
    const float* __restrict__ rnn_ws, const float* __restrict__ f_g,
    const float* __restrict__ f_beta, const float* __restrict__ f_W,
    const float* __restrict__ f_b, float* __restrict__ value_out)
{
    const int r = blockIdx.x * 4 + (threadIdx.x >> 6);  // row = n*8 + i
    const int j = threadIdx.x & 63;
    const int n = r >> 3, i = r & 7;
    const int b = n >> 9, t = n & 511;
    const int seq = b * A_ + i;

    float h = rnn_ws[((size_t)seq * T_ + t) * 64 + j];
    float m = red64(h) * (1.0f / 64.0f);
    float d = h - m;
    float v = red64(d * d) * (1.0f / 64.0f);
    float nrm = d * rsqrtf(v + 1e-5f) * f_g[j] + f_beta[j];
    float p = red64(nrm * f_W[j]);
    if (j == 0) value_out[r] = p + f_b[0];
}

// ---------------- launch ----------------

extern "C" void kernel_launch(void* const* d_in, const int* in_sizes, int n_in,
                              void* d_out, int out_size, void* d_ws, size_t ws_size,
                              hipStream_t stream) {
    (void)in_sizes; (void)n_in; (void)out_size; (void)ws_size;

    const float* states   = (const float*)d_in[0];
    const float* actions  = (const float*)d_in[1];
    const float* h0       = (const float*)d_in[2];
    const float* sa_W     = (const float*)d_in[3];
    const float* sa_b     = (const float*)d_in[4];
    const float* sa_g     = (const float*)d_in[5];
    const float* sa_beta  = (const float*)d_in[6];
    const float* se_W     = (const float*)d_in[7];
    const float* se_b     = (const float*)d_in[8];
    const float* se_g     = (const float*)d_in[9];
    const float* se_beta  = (const float*)d_in[10];
    const float* key_W    = (const float*)d_in[11];
    const float* query_W  = (const float*)d_in[12];
    const float* val_W    = (const float*)d_in[13];
    const float* av_g     = (const float*)d_in[14];
    const float* av_beta  = (const float*)d_in[15];
    const float* lin1_W   = (const float*)d_in[16];
    const float* lin1_b   = (const float*)d_in[17];
    const float* lin_g    = (const float*)d_in[18];
    const float* lin_beta = (const float*)d_in[19];
    const float* lin2_W   = (const float*)d_in[20];
    const float* lin2_b   = (const float*)d_in[21];
    const float* avl_g    = (const float*)d_in[22];
    const float* avl_beta = (const float*)d_in[23];
    const float* q_W      = (const float*)d_in[24];
    const float* q_b      = (const float*)d_in[25];
    const float* q_g      = (const float*)d_in[26];
    const float* q_beta   = (const float*)d_in[27];
    const float* c_W      = (const float*)d_in[28];
    const float* c_b      = (const float*)d_in[29];
    const float* gru_Wih  = (const float*)d_in[30];
    const float* gru_Whh  = (const float*)d_in[31];
    const float* gru_bih  = (const float*)d_in[32];
    const float* gru_bhh  = (const float*)d_in[33];
    const float* f_g      = (const float*)d_in[34];
    const float* f_beta   = (const float*)d_in[35];
    const float* f_W      = (const float*)d_in[36];
    const float* f_b      = (const float*)d_in[37];

    float* out = (float*)d_out;
    float* value_out  = out;                          // 131072
    float* weight_out = out + (size_t)NTOK * A_;      // 917504
    float* hT_out     = out + (size_t)NTOK * A_ * 8;  // 16384

    float* gi_ws  = (float*)d_ws;                     // [256][512][192] f32 = 96 MiB
    float* rnn_ws = gi_ws + (size_t)GI_FLOATS;        // [256][512][64]  f32 = 32 MiB

    token_kernel<<<NTOK / TPB, 128, 0, stream>>>(
        states, actions,
        sa_W, sa_b, sa_g, sa_beta,
        se_W, se_b, se_g, se_beta,
        key_W, query_W, val_W,
        av_g, av_beta,
        lin1_W, lin1_b, lin_g, lin_beta,
        lin2_W, lin2_b,
        avl_g, avl_beta,
        q_W, q_b, q_g, q_beta,
        c_W, c_b,
        gru_Wih, gru_bih,
        weight_out, gi_ws);

    gru_kernel<<<NSEQ, 192, 0, stream>>>(h0, gru_Whh, gru_bhh, gi_ws, rnn_ws, hT_out);

    value_kernel<<<(NTOK * A_) / 4, 256, 0, stream>>>(
        rnn_ws, f_g, f_beta, f_W, f_b, value_out);
}